// Round 5
// baseline (158.417 us; speedup 1.0000x reference)
//
#include <hip/hip_runtime.h>

#define DI static __device__ __forceinline__

typedef __attribute__((ext_vector_type(8))) short short8;  // 8 bf16 in 4 VGPRs
typedef __attribute__((ext_vector_type(4))) float f32x4;

// fp32 -> bf16 round-to-nearest-even
DI unsigned short f2bf(float f) {
    union { float f; unsigned int u; } v; v.f = f;
    unsigned int r = v.u + 0x7FFFu + ((v.u >> 16) & 1u);
    return (unsigned short)(r >> 16);
}

// async global->LDS, 16B per lane. LDS dest must be wave-uniform base + lane*16.
DI void gload_lds16(const void* g, void* l) {
    __builtin_amdgcn_global_load_lds(
        (const __attribute__((address_space(1))) void*)g,
        (__attribute__((address_space(3))) void*)l, 16, 0, 0);
}

// swizzled LDS fragment read for 128B-row tiles (attention)
DI short8 ldsfrag(const void* base, int row, int bytecol) {
    return *(const short8*)((const char*)base + row * 128 + (bytecol ^ ((row & 7) << 4)));
}

// ---------------------------------------------------------------------------
// Kernel 1: fp32 -> bf16 conversion for x and the 4 weight matrices
// ---------------------------------------------------------------------------
__global__ __launch_bounds__(256) void k_cvt(
    const float* __restrict__ x, const float* __restrict__ wq,
    const float* __restrict__ wk, const float* __restrict__ wv,
    const float* __restrict__ wo,
    unsigned short* __restrict__ xb, unsigned short* __restrict__ wqb,
    unsigned short* __restrict__ wkb, unsigned short* __restrict__ wvb,
    unsigned short* __restrict__ wob)
{
    const float* src; unsigned short* dst; int n;
    switch (blockIdx.y) {
        case 0:  src = x;  dst = xb;  n = 8388608; break;
        case 1:  src = wq; dst = wqb; n = 1048576; break;
        case 2:  src = wk; dst = wkb; n = 1048576; break;
        case 3:  src = wv; dst = wvb; n = 1048576; break;
        default: src = wo; dst = wob; n = 1048576; break;
    }
    int idx = (blockIdx.x * 256 + threadIdx.x) * 4;
    if (idx >= n) return;
    float4 v = *(const float4*)(src + idx);
    unsigned long long o = (unsigned long long)f2bf(v.x)
        | ((unsigned long long)f2bf(v.y) << 16)
        | ((unsigned long long)f2bf(v.z) << 32)
        | ((unsigned long long)f2bf(v.w) << 48);
    *(unsigned long long*)(dst + idx) = o;
}

// ---------------------------------------------------------------------------
// 256x256 GEMM core, BK=32, K=1024. C[i][j] = sum_k A[i][k]*B[j][k] (NT).
// 8 waves (2M x 4N), per-wave C = 128x64 = 8x4 16x16x32 frags.
// 3 LDS buffers x (A 16KB + B 16KB) = 96KB. Counted-vmcnt pipeline:
//   body ks: vmcnt(4) [tile ks landed; ks+1 in flight] -> s_barrier ->
//            issue tile ks+2 into buf[(ks+2)%3] (reads of it done last body,
//            proven: every ds_read's data is consumed by an MFMA before the
//            barrier) -> 12 ds_read_b128 -> 32 MFMA (setprio-wrapped).
// LDS rows are 64B (32 bf16); slot swizzle slot^=(row>>1)&3 applied on the
// pre-swizzled global source AND the fragment read (R3: conflicts == 0).
// ---------------------------------------------------------------------------
DI void gemm256_core(const unsigned short* __restrict__ Ag,
                     const unsigned short* __restrict__ Bg,
                     int m0, int n0, char* smem, f32x4 acc[8][4])
{
    const int t = threadIdx.x, lane = t & 63;
    const int wid = t >> 6, wr = wid >> 2, wc = wid & 3;
    const int kl = lane & 15, hi = lane >> 4;

#pragma unroll
    for (int m = 0; m < 8; ++m)
#pragma unroll
        for (int n = 0; n < 4; ++n)
            acc[m][n] = f32x4{0.f, 0.f, 0.f, 0.f};

    // staging: per operand 1024 chunks of 16B; thread t covers c0=t, c1=t+512
    // chunk c: row = c>>2 (64B rows), slot = c&3, src slot = slot ^ ((row>>1)&3)
    const int c0 = t, c1 = t + 512;
    const int r0 = c0 >> 2, r1 = c1 >> 2;
    const int s0 = ((c0 & 3) ^ ((r0 >> 1) & 3)) * 8;
    const int s1 = ((c1 & 3) ^ ((r1 >> 1) & 3)) * 8;
    const unsigned short* pa0 = Ag + (long)(m0 + r0) * 1024 + s0;
    const unsigned short* pa1 = Ag + (long)(m0 + r1) * 1024 + s1;
    const unsigned short* pb0 = Bg + (long)(n0 + r0) * 1024 + s0;
    const unsigned short* pb1 = Bg + (long)(n0 + r1) * 1024 + s1;

#define STAGE(TILE, BUF) do {                                          \
        char* _sa = smem + (BUF) * 32768;                              \
        gload_lds16(pa0 + (TILE) * 32, _sa + c0 * 16);                 \
        gload_lds16(pa1 + (TILE) * 32, _sa + c1 * 16);                 \
        gload_lds16(pb0 + (TILE) * 32, _sa + 16384 + c0 * 16);         \
        gload_lds16(pb1 + (TILE) * 32, _sa + 16384 + c1 * 16);         \
    } while (0)

    // prologue: tiles 0 and 1 in flight
    STAGE(0, 0);
    STAGE(1, 1);

    // fragment read offsets (swizzle key (kl>>1)&3 is m/n-independent)
    const int swz = ((hi ^ ((kl >> 1) & 3)) << 4);
    const int aoff = (wr * 128 + kl) * 64 + swz;
    const int boff = 16384 + (wc * 64 + kl) * 64 + swz;

#define KSTEP(KS, CUR, PRE, ISSUE, VM) do {                                   \
        asm volatile("s_waitcnt vmcnt(" VM ")" ::: "memory");                 \
        __builtin_amdgcn_s_barrier();                                         \
        __builtin_amdgcn_sched_barrier(0);                                    \
        if (ISSUE) STAGE((KS) + 2, PRE);                                      \
        const char* _ab = smem + (CUR) * 32768 + aoff;                        \
        const char* _bb = smem + (CUR) * 32768 + boff;                        \
        short8 _fa[8], _fb[4];                                                \
        _Pragma("unroll")                                                     \
        for (int m = 0; m < 8; ++m) _fa[m] = *(const short8*)(_ab + m * 1024);\
        _Pragma("unroll")                                                     \
        for (int n = 0; n < 4; ++n) _fb[n] = *(const short8*)(_bb + n * 1024);\
        __builtin_amdgcn_s_setprio(1);                                        \
        _Pragma("unroll")                                                     \
        for (int m = 0; m < 8; ++m)                                           \
        _Pragma("unroll")                                                     \
            for (int n = 0; n < 4; ++n)                                       \
                acc[m][n] = __builtin_amdgcn_mfma_f32_16x16x32_bf16(          \
                    _fa[m], _fb[n], acc[m][n], 0, 0, 0);                      \
        __builtin_amdgcn_s_setprio(0);                                        \
    } while (0)

    for (int u = 0; u < 10; ++u) {
        const int ks = u * 3;
        KSTEP(ks + 0, 0, 2, 1, "4");
        KSTEP(ks + 1, 1, 0, 1, "4");
        KSTEP(ks + 2, 2, 1, 1, "4");
    }
    KSTEP(30, 0, 2, 0, "4");
    KSTEP(31, 1, 0, 0, "0");
#undef KSTEP
#undef STAGE
}

// ---------------------------------------------------------------------------
// Kernel 2: fused QKV projection, 256^2 tiles. grid (32, 12): y = w*4 + nb.
// Output layout (B,H,T,hd) bf16. Q gets the 1/sqrt(hd)=0.125 scale folded in.
// ---------------------------------------------------------------------------
__global__ __launch_bounds__(512, 2) void k_gemm_qkv(
    const unsigned short* __restrict__ xb,
    const unsigned short* __restrict__ wqb, const unsigned short* __restrict__ wkb,
    const unsigned short* __restrict__ wvb,
    unsigned short* __restrict__ Qo, unsigned short* __restrict__ Ko,
    unsigned short* __restrict__ Vo)
{
    extern __shared__ char smem[];
    const int bx = blockIdx.x, by = blockIdx.y;
    const int w = by >> 2, nb = by & 3;
    const unsigned short* Bw = (w == 0) ? wqb : ((w == 1) ? wkb : wvb);
    unsigned short* Ow = (w == 0) ? Qo : ((w == 1) ? Ko : Vo);
    const float sc = (w == 0) ? 0.125f : 1.0f;

    f32x4 acc[8][4];
    gemm256_core(xb, Bw, bx * 256, nb * 256, smem, acc);

    const int t = threadIdx.x, lane = t & 63, wid = t >> 6;
    const int wr = wid >> 2, wc = wid & 3, kl = lane & 15, hi = lane >> 4;
    const int h = nb * 4 + wc;       // head (wave-uniform)
#pragma unroll
    for (int m = 0; m < 8; ++m)
#pragma unroll
        for (int r = 0; r < 4; ++r) {
            int grow = bx * 256 + wr * 128 + m * 16 + hi * 4 + r;
            int bi = grow >> 12, tt = grow & 4095;
            unsigned short* rowp = Ow + ((long)(bi * 16 + h) * 4096 + tt) * 64;
#pragma unroll
            for (int n = 0; n < 4; ++n)
                rowp[n * 16 + kl] = f2bf(acc[m][n][r] * sc);
        }
}

// ---------------------------------------------------------------------------
// Kernel 3: V (B,H,T,hd) -> VT (B,H,hd,T), LDS-tiled 64x64 transpose.
// ---------------------------------------------------------------------------
__global__ __launch_bounds__(256) void k_vtrans(const unsigned short* __restrict__ V,
                                                unsigned short* __restrict__ VT)
{
    __shared__ unsigned short S[64 * 64];
    const int t = threadIdx.x;
    const int bh = blockIdx.y, tb = blockIdx.x;
    const unsigned short* src = V + ((long)bh * 4096 + tb * 64) * 64;
    unsigned short* dst = VT + (long)bh * 4096 * 64 + tb * 64;
    char* sb = (char*)S;
#pragma unroll
    for (int c = t; c < 512; c += 256) {
        int r = c >> 3, o8 = (c & 7) * 8;
        *(uint4*)(sb + r * 128 + ((o8 * 2) ^ (((r >> 3) & 7) << 4))) =
            *(const uint4*)(src + r * 64 + o8);
    }
    __syncthreads();
#pragma unroll
    for (int c = t; c < 512; c += 256) {
        int d = c >> 3, t0 = (c & 7) * 8;
        uint4 val;
        unsigned short* pv = (unsigned short*)&val;
#pragma unroll
        for (int jj = 0; jj < 8; ++jj) {
            int row = t0 + jj;
            pv[jj] = *(const unsigned short*)(sb + row * 128 +
                        ((d * 2) ^ (((row >> 3) & 7) << 4)));
        }
        *(uint4*)(dst + (long)d * 4096 + t0) = val;
    }
}

// ---------------------------------------------------------------------------
// Kernel 4: banded sliding-window attention (unchanged from round 2).
// ---------------------------------------------------------------------------
__global__ __launch_bounds__(256) void k_attn(
    const unsigned short* __restrict__ Q, const unsigned short* __restrict__ K,
    const unsigned short* __restrict__ VT, unsigned short* __restrict__ AO)
{
    __shared__ unsigned short Qs[4096];            // reused as P after prologue
    __shared__ unsigned short Ks[2][4096], Vs[2][4096];
    const int t = threadIdx.x, lane = t & 63, wid = t >> 6;
    const int kl = lane & 15, hi = lane >> 4;
    const int bid = blockIdx.x;
    const int sid = (bid & 7) * 256 + (bid >> 3);  // XCD-chunked (2048%8==0)
    const int i = sid & 63, bh = sid >> 6;
    const int b = bh >> 4, h = bh & 15;
    const char* qg = (const char*)(Q + ((long)bh * 4096 + i * 64) * 64);
    const char* kg = (const char*)(K + (long)bh * 4096 * 64);
    const char* vg = (const char*)(VT + (long)bh * 64 * 4096);

    const int c0 = t, c1 = t + 256;
    const int r0 = c0 >> 3, sw0 = ((c0 & 7) * 16) ^ ((r0 & 7) << 4);
    const int r1 = c1 >> 3, sw1 = ((c1 & 7) * 16) ^ ((r1 & 7) << 4);
    const char* kg0 = kg + r0 * 128 + sw0;    // + j*8192
    const char* kg1 = kg + r1 * 128 + sw1;
    const char* vg0 = vg + r0 * 8192 + sw0;   // + j*128
    const char* vg1 = vg + r1 * 8192 + sw1;

    const int j0 = (i >= 8) ? i - 8 : 0;

    gload_lds16(qg + r0 * 128 + sw0, (char*)Qs + c0 * 16);
    gload_lds16(qg + r1 * 128 + sw1, (char*)Qs + c1 * 16);
    gload_lds16(kg0 + j0 * 8192, (char*)Ks[0] + c0 * 16);
    gload_lds16(kg1 + j0 * 8192, (char*)Ks[0] + c1 * 16);
    gload_lds16(vg0 + j0 * 128,  (char*)Vs[0] + c0 * 16);
    gload_lds16(vg1 + j0 * 128,  (char*)Vs[0] + c1 * 16);
    __syncthreads();

    short8 aq[2];
    aq[0] = ldsfrag(Qs, wid * 16 + kl, hi * 16);
    aq[1] = ldsfrag(Qs, wid * 16 + kl, 64 + hi * 16);

    float lsum[4] = {0.f, 0.f, 0.f, 0.f};
    f32x4 o[4];
#pragma unroll
    for (int nt = 0; nt < 4; ++nt) o[nt] = f32x4{0.f, 0.f, 0.f, 0.f};

    const int qrow = wid * 16 + hi * 4;       // + r
    char* pw = (char*)Qs + wid * 2048;        // per-wave P region (own Q rows)

    for (int j = j0; j <= i; ++j) {
        const int buf = (j - j0) & 1;
        if (j < i) {                           // deferred prefetch of j+1
            const int nb = buf ^ 1;
            gload_lds16(kg0 + (j + 1) * 8192, (char*)Ks[nb] + c0 * 16);
            gload_lds16(kg1 + (j + 1) * 8192, (char*)Ks[nb] + c1 * 16);
            gload_lds16(vg0 + (j + 1) * 128,  (char*)Vs[nb] + c0 * 16);
            gload_lds16(vg1 + (j + 1) * 128,  (char*)Vs[nb] + c1 * 16);
        }

        f32x4 s[4];
#pragma unroll
        for (int nt = 0; nt < 4; ++nt) {
            s[nt] = f32x4{0.f, 0.f, 0.f, 0.f};
#pragma unroll
            for (int kk = 0; kk < 2; ++kk)
                s[nt] = __builtin_amdgcn_mfma_f32_16x16x32_bf16(
                    aq[kk], ldsfrag(Ks[buf], nt * 16 + kl, kk * 64 + hi * 16),
                    s[nt], 0, 0, 0);
        }

        if (j == i) {               // diagonal: valid iff key <= q
#pragma unroll
            for (int nt = 0; nt < 4; ++nt) {
                int key = nt * 16 + kl;
#pragma unroll
                for (int r = 0; r < 4; ++r)
                    if (key > qrow + r) s[nt][r] = -1e9f;
            }
        } else if (i - j == 8) {    // far edge: valid iff key > q
#pragma unroll
            for (int nt = 0; nt < 4; ++nt) {
                int key = nt * 16 + kl;
#pragma unroll
                for (int r = 0; r < 4; ++r)
                    if (key <= qrow + r) s[nt][r] = -1e9f;
            }
        }

#pragma unroll
        for (int nt = 0; nt < 4; ++nt)
#pragma unroll
            for (int r = 0; r < 4; ++r) {
                float p = __expf(s[nt][r]);
                s[nt][r] = p;
                lsum[r] += p;
            }

#pragma unroll
        for (int nt = 0; nt < 4; ++nt)
#pragma unroll
            for (int r = 0; r < 4; ++r) {
                int q = hi * 4 + r;
                int colb = (nt * 16 + kl) * 2;
                *(unsigned short*)(pw + q * 128 + (colb ^ ((q & 7) << 4))) =
                    f2bf(s[nt][r]);
            }

        short8 pa0 = ldsfrag(pw, kl, hi * 16);
        short8 pa1 = ldsfrag(pw, kl, 64 + hi * 16);
#pragma unroll
        for (int nt = 0; nt < 4; ++nt) {
            o[nt] = __builtin_amdgcn_mfma_f32_16x16x32_bf16(
                pa0, ldsfrag(Vs[buf], nt * 16 + kl, hi * 16), o[nt], 0, 0, 0);
            o[nt] = __builtin_amdgcn_mfma_f32_16x16x32_bf16(
                pa1, ldsfrag(Vs[buf], nt * 16 + kl, 64 + hi * 16), o[nt], 0, 0, 0);
        }

        __syncthreads();
    }

#pragma unroll
    for (int d = 1; d < 16; d <<= 1)
#pragma unroll
        for (int r = 0; r < 4; ++r) lsum[r] += __shfl_xor(lsum[r], d);

    float inv[4];
#pragma unroll
    for (int r = 0; r < 4; ++r) inv[r] = 1.0f / lsum[r];
#pragma unroll
    for (int r = 0; r < 4; ++r) {
        int tt = i * 64 + wid * 16 + hi * 4 + r;
        unsigned short* rowp = AO + ((long)(b * 4096 + tt)) * 1024 + h * 64;
#pragma unroll
        for (int nt = 0; nt < 4; ++nt)
            rowp[nt * 16 + kl] = f2bf(o[nt][r] * inv[r]);
    }
}

// ---------------------------------------------------------------------------
// Kernel 5: output projection (256^2 tiles) -> fp32 d_out. grid (32, 4).
// ---------------------------------------------------------------------------
__global__ __launch_bounds__(512, 2) void k_gemm_out(
    const unsigned short* __restrict__ AO, const unsigned short* __restrict__ wob,
    float* __restrict__ out)
{
    extern __shared__ char smem[];
    const int bx = blockIdx.x, nb = blockIdx.y;
    f32x4 acc[8][4];
    gemm256_core(AO, wob, bx * 256, nb * 256, smem, acc);

    const int t = threadIdx.x, lane = t & 63, wid = t >> 6;
    const int wr = wid >> 2, wc = wid & 3, kl = lane & 15, hi = lane >> 4;
#pragma unroll
    for (int m = 0; m < 8; ++m)
#pragma unroll
        for (int r = 0; r < 4; ++r) {
            int grow = bx * 256 + wr * 128 + m * 16 + hi * 4 + r;
            float* rowp = out + (long)grow * 1024 + nb * 256 + wc * 64;
#pragma unroll
            for (int n = 0; n < 4; ++n)
                rowp[n * 16 + kl] = acc[m][n][r];
        }
}

// ---------------------------------------------------------------------------
extern "C" void kernel_launch(void* const* d_in, const int* in_sizes, int n_in,
                              void* d_out, int out_size, void* d_ws, size_t ws_size,
                              hipStream_t stream) {
    const float* x  = (const float*)d_in[0];
    const float* wq = (const float*)d_in[1];
    const float* wk = (const float*)d_in[2];
    const float* wv = (const float*)d_in[3];
    const float* wo = (const float*)d_in[4];

    char* ws = (char*)d_ws;
    const size_t MB = 1024 * 1024;
    unsigned short* xb  = (unsigned short*)(ws);            // 16 MB, reused as AO
    unsigned short* wqb = (unsigned short*)(ws + 16 * MB);  // 2 MB
    unsigned short* wkb = (unsigned short*)(ws + 18 * MB);
    unsigned short* wvb = (unsigned short*)(ws + 20 * MB);
    unsigned short* wob = (unsigned short*)(ws + 22 * MB);
    unsigned short* Qp  = (unsigned short*)(ws + 24 * MB);  // 16 MB each
    unsigned short* Kp  = (unsigned short*)(ws + 40 * MB);
    unsigned short* Vp  = (unsigned short*)(ws + 56 * MB);
    unsigned short* VTp = (unsigned short*)(ws + 72 * MB);  // end 88 MB
    unsigned short* AOp = xb;  // x no longer needed after QKV GEMM

    hipFuncSetAttribute((const void*)k_gemm_qkv,
                        hipFuncAttributeMaxDynamicSharedMemorySize, 98304);
    hipFuncSetAttribute((const void*)k_gemm_out,
                        hipFuncAttributeMaxDynamicSharedMemorySize, 98304);

    dim3 blk(256);
    k_cvt<<<dim3(8192, 5), blk, 0, stream>>>(x, wq, wk, wv, wo,
                                             xb, wqb, wkb, wvb, wob);
    k_gemm_qkv<<<dim3(32, 12), 512, 98304, stream>>>(xb, wqb, wkb, wvb,
                                                     Qp, Kp, Vp);
    k_vtrans<<<dim3(64, 32), blk, 0, stream>>>(Vp, VTp);
    k_attn<<<2048, blk, 0, stream>>>(Qp, Kp, VTp, AOp);
    k_gemm_out<<<dim3(32, 4), 512, 98304, stream>>>(AOp, wob, (float*)d_out);
}

// Round 6
// 148.445 us; speedup vs baseline: 1.0672x; 1.0672x over previous
//
#include <hip/hip_runtime.h>

#define DI static __device__ __forceinline__

typedef __attribute__((ext_vector_type(8))) short short8;  // 8 bf16 in 4 VGPRs
typedef __attribute__((ext_vector_type(4))) float f32x4;

// fp32 -> bf16 round-to-nearest-even
DI unsigned short f2bf(float f) {
    union { float f; unsigned int u; } v; v.f = f;
    unsigned int r = v.u + 0x7FFFu + ((v.u >> 16) & 1u);
    return (unsigned short)(r >> 16);
}

// async global->LDS, 16B per lane. LDS dest must be wave-uniform base + lane*16.
DI void gload_lds16(const void* g, void* l) {
    __builtin_amdgcn_global_load_lds(
        (const __attribute__((address_space(1))) void*)g,
        (__attribute__((address_space(3))) void*)l, 16, 0, 0);
}

// swizzled LDS fragment read for 128B-row tiles (attention)
DI short8 ldsfrag(const void* base, int row, int bytecol) {
    return *(const short8*)((const char*)base + row * 128 + (bytecol ^ ((row & 7) << 4)));
}

// ---------------------------------------------------------------------------
// Kernel 1: fp32 -> bf16 conversion for x and the 4 weight matrices
// ---------------------------------------------------------------------------
__global__ __launch_bounds__(256) void k_cvt(
    const float* __restrict__ x, const float* __restrict__ wq,
    const float* __restrict__ wk, const float* __restrict__ wv,
    const float* __restrict__ wo,
    unsigned short* __restrict__ xb, unsigned short* __restrict__ wqb,
    unsigned short* __restrict__ wkb, unsigned short* __restrict__ wvb,
    unsigned short* __restrict__ wob)
{
    const float* src; unsigned short* dst; int n;
    switch (blockIdx.y) {
        case 0:  src = x;  dst = xb;  n = 8388608; break;
        case 1:  src = wq; dst = wqb; n = 1048576; break;
        case 2:  src = wk; dst = wkb; n = 1048576; break;
        case 3:  src = wv; dst = wvb; n = 1048576; break;
        default: src = wo; dst = wob; n = 1048576; break;
    }
    int idx = (blockIdx.x * 256 + threadIdx.x) * 4;
    if (idx >= n) return;
    float4 v = *(const float4*)(src + idx);
    unsigned long long o = (unsigned long long)f2bf(v.x)
        | ((unsigned long long)f2bf(v.y) << 16)
        | ((unsigned long long)f2bf(v.z) << 32)
        | ((unsigned long long)f2bf(v.w) << 48);
    *(unsigned long long*)(dst + idx) = o;
}

// ---------------------------------------------------------------------------
// 128x256 GEMM core, BK=32, K=1024. C[i][j] = sum_k A[i][k]*B[j][k] (NT).
// 8 waves (2M x 4N), per-wave C = 64x64 = 4x4 16x16x32 frags.
// 3 LDS buffers x (A 8KB + B 16KB) = 72KB -> 2 blocks/CU co-resident
// (cross-block phase overlap). Counted-vmcnt pipeline (proven R5 schedule):
//   body ks: vmcnt(3) [tile ks landed; ks+1 in flight] -> s_barrier ->
//            issue tile ks+2 into buf[(ks+2)%3] (its reads finished at step
//            ks-1, fenced by this barrier) -> 8 ds_read_b128 -> 16 MFMA.
// LDS rows are 64B (32 bf16); slot swizzle slot^=(row>>1)&3 on pre-swizzled
// global source AND fragment read (R3/R5: conflicts == 0).
// ---------------------------------------------------------------------------
DI void gemm_core(const unsigned short* __restrict__ Ag,
                  const unsigned short* __restrict__ Bg,
                  int m0, int n0, char* smem, f32x4 acc[4][4])
{
    const int t = threadIdx.x, lane = t & 63;
    const int wid = t >> 6, wr = wid >> 2, wc = wid & 3;
    const int kl = lane & 15, hi = lane >> 4;

#pragma unroll
    for (int m = 0; m < 4; ++m)
#pragma unroll
        for (int n = 0; n < 4; ++n)
            acc[m][n] = f32x4{0.f, 0.f, 0.f, 0.f};

    // staging: A = 512 chunks of 16B (1/thread), B = 1024 chunks (2/thread)
    // chunk c: row = c>>2 (64B rows), slot = c&3, src slot = slot ^ ((row>>1)&3)
    const int ca  = t,       ra  = ca  >> 2, sa  = ((ca  & 3) ^ ((ra  >> 1) & 3)) * 8;
    const int cb0 = t,       rb0 = cb0 >> 2, sb0 = ((cb0 & 3) ^ ((rb0 >> 1) & 3)) * 8;
    const int cb1 = t + 512, rb1 = cb1 >> 2, sb1 = ((cb1 & 3) ^ ((rb1 >> 1) & 3)) * 8;
    const unsigned short* pa  = Ag + (long)(m0 + ra)  * 1024 + sa;
    const unsigned short* pb0 = Bg + (long)(n0 + rb0) * 1024 + sb0;
    const unsigned short* pb1 = Bg + (long)(n0 + rb1) * 1024 + sb1;

#define STAGE(TILE, BUF) do {                                          \
        char* _sb = smem + (BUF) * 24576;                              \
        gload_lds16(pa  + (TILE) * 32, _sb + ca * 16);                 \
        gload_lds16(pb0 + (TILE) * 32, _sb + 8192 + cb0 * 16);         \
        gload_lds16(pb1 + (TILE) * 32, _sb + 8192 + cb1 * 16);         \
    } while (0)

    // prologue: tiles 0 and 1 in flight
    STAGE(0, 0);
    STAGE(1, 1);

    // fragment read offsets (swizzle key (kl>>1)&3; row = base16 + kl)
    const int swz = ((hi ^ ((kl >> 1) & 3)) << 4);
    const int aoff = (wr * 64 + kl) * 64 + swz;           // + m*1024
    const int boff = 8192 + (wc * 64 + kl) * 64 + swz;    // + n*1024

#define KSTEP(KS, CUR, PRE, ISSUE, VM) do {                                   \
        asm volatile("s_waitcnt vmcnt(" VM ")" ::: "memory");                 \
        __builtin_amdgcn_s_barrier();                                         \
        __builtin_amdgcn_sched_barrier(0);                                    \
        if (ISSUE) STAGE((KS) + 2, PRE);                                      \
        const char* _ab = smem + (CUR) * 24576 + aoff;                        \
        const char* _bb = smem + (CUR) * 24576 + boff;                        \
        short8 _fa[4], _fb[4];                                                \
        _Pragma("unroll")                                                     \
        for (int m = 0; m < 4; ++m) _fa[m] = *(const short8*)(_ab + m * 1024);\
        _Pragma("unroll")                                                     \
        for (int n = 0; n < 4; ++n) _fb[n] = *(const short8*)(_bb + n * 1024);\
        __builtin_amdgcn_s_setprio(1);                                        \
        _Pragma("unroll")                                                     \
        for (int m = 0; m < 4; ++m)                                           \
        _Pragma("unroll")                                                     \
            for (int n = 0; n < 4; ++n)                                       \
                acc[m][n] = __builtin_amdgcn_mfma_f32_16x16x32_bf16(          \
                    _fa[m], _fb[n], acc[m][n], 0, 0, 0);                      \
        __builtin_amdgcn_s_setprio(0);                                        \
    } while (0)

    for (int u = 0; u < 10; ++u) {
        const int ks = u * 3;
        KSTEP(ks + 0, 0, 2, 1, "3");
        KSTEP(ks + 1, 1, 0, 1, "3");
        KSTEP(ks + 2, 2, 1, 1, "3");
    }
    KSTEP(30, 0, 2, 0, "3");
    KSTEP(31, 1, 0, 0, "0");
#undef KSTEP
#undef STAGE
}

// ---------------------------------------------------------------------------
// Kernel 2: fused QKV projection, 128x256 tiles. grid (64, 12): y = w*4 + nb.
// Output layout (B,H,T,hd) bf16. Q gets the 1/sqrt(hd)=0.125 scale folded in.
// ---------------------------------------------------------------------------
__global__ __launch_bounds__(512, 4) void k_gemm_qkv(
    const unsigned short* __restrict__ xb,
    const unsigned short* __restrict__ wqb, const unsigned short* __restrict__ wkb,
    const unsigned short* __restrict__ wvb,
    unsigned short* __restrict__ Qo, unsigned short* __restrict__ Ko,
    unsigned short* __restrict__ Vo)
{
    extern __shared__ char smem[];
    const int bx = blockIdx.x, by = blockIdx.y;
    const int w = by >> 2, nb = by & 3;
    const unsigned short* Bw = (w == 0) ? wqb : ((w == 1) ? wkb : wvb);
    unsigned short* Ow = (w == 0) ? Qo : ((w == 1) ? Ko : Vo);
    const float sc = (w == 0) ? 0.125f : 1.0f;

    f32x4 acc[4][4];
    gemm_core(xb, Bw, bx * 128, nb * 256, smem, acc);

    const int t = threadIdx.x, lane = t & 63, wid = t >> 6;
    const int wr = wid >> 2, wc = wid & 3, kl = lane & 15, hi = lane >> 4;
    const int h = nb * 4 + wc;       // head (wave-uniform)
#pragma unroll
    for (int m = 0; m < 4; ++m)
#pragma unroll
        for (int r = 0; r < 4; ++r) {
            int grow = bx * 128 + wr * 64 + m * 16 + hi * 4 + r;
            int bi = grow >> 12, tt = grow & 4095;
            unsigned short* rowp = Ow + ((long)(bi * 16 + h) * 4096 + tt) * 64;
#pragma unroll
            for (int n = 0; n < 4; ++n)
                rowp[n * 16 + kl] = f2bf(acc[m][n][r] * sc);
        }
}

// ---------------------------------------------------------------------------
// Kernel 3: V (B,H,T,hd) -> VT (B,H,hd,T), LDS-tiled 64x64 transpose.
// ---------------------------------------------------------------------------
__global__ __launch_bounds__(256) void k_vtrans(const unsigned short* __restrict__ V,
                                                unsigned short* __restrict__ VT)
{
    __shared__ unsigned short S[64 * 64];
    const int t = threadIdx.x;
    const int bh = blockIdx.y, tb = blockIdx.x;
    const unsigned short* src = V + ((long)bh * 4096 + tb * 64) * 64;
    unsigned short* dst = VT + (long)bh * 4096 * 64 + tb * 64;
    char* sb = (char*)S;
#pragma unroll
    for (int c = t; c < 512; c += 256) {
        int r = c >> 3, o8 = (c & 7) * 8;
        *(uint4*)(sb + r * 128 + ((o8 * 2) ^ (((r >> 3) & 7) << 4))) =
            *(const uint4*)(src + r * 64 + o8);
    }
    __syncthreads();
#pragma unroll
    for (int c = t; c < 512; c += 256) {
        int d = c >> 3, t0 = (c & 7) * 8;
        uint4 val;
        unsigned short* pv = (unsigned short*)&val;
#pragma unroll
        for (int jj = 0; jj < 8; ++jj) {
            int row = t0 + jj;
            pv[jj] = *(const unsigned short*)(sb + row * 128 +
                        ((d * 2) ^ (((row >> 3) & 7) << 4)));
        }
        *(uint4*)(dst + (long)d * 4096 + t0) = val;
    }
}

// ---------------------------------------------------------------------------
// Kernel 4: banded sliding-window attention (unchanged).
// ---------------------------------------------------------------------------
__global__ __launch_bounds__(256) void k_attn(
    const unsigned short* __restrict__ Q, const unsigned short* __restrict__ K,
    const unsigned short* __restrict__ VT, unsigned short* __restrict__ AO)
{
    __shared__ unsigned short Qs[4096];            // reused as P after prologue
    __shared__ unsigned short Ks[2][4096], Vs[2][4096];
    const int t = threadIdx.x, lane = t & 63, wid = t >> 6;
    const int kl = lane & 15, hi = lane >> 4;
    const int bid = blockIdx.x;
    const int sid = (bid & 7) * 256 + (bid >> 3);  // XCD-chunked (2048%8==0)
    const int i = sid & 63, bh = sid >> 6;
    const int b = bh >> 4, h = bh & 15;
    const char* qg = (const char*)(Q + ((long)bh * 4096 + i * 64) * 64);
    const char* kg = (const char*)(K + (long)bh * 4096 * 64);
    const char* vg = (const char*)(VT + (long)bh * 64 * 4096);

    const int c0 = t, c1 = t + 256;
    const int r0 = c0 >> 3, sw0 = ((c0 & 7) * 16) ^ ((r0 & 7) << 4);
    const int r1 = c1 >> 3, sw1 = ((c1 & 7) * 16) ^ ((r1 & 7) << 4);
    const char* kg0 = kg + r0 * 128 + sw0;    // + j*8192
    const char* kg1 = kg + r1 * 128 + sw1;
    const char* vg0 = vg + r0 * 8192 + sw0;   // + j*128
    const char* vg1 = vg + r1 * 8192 + sw1;

    const int j0 = (i >= 8) ? i - 8 : 0;

    gload_lds16(qg + r0 * 128 + sw0, (char*)Qs + c0 * 16);
    gload_lds16(qg + r1 * 128 + sw1, (char*)Qs + c1 * 16);
    gload_lds16(kg0 + j0 * 8192, (char*)Ks[0] + c0 * 16);
    gload_lds16(kg1 + j0 * 8192, (char*)Ks[0] + c1 * 16);
    gload_lds16(vg0 + j0 * 128,  (char*)Vs[0] + c0 * 16);
    gload_lds16(vg1 + j0 * 128,  (char*)Vs[0] + c1 * 16);
    __syncthreads();

    short8 aq[2];
    aq[0] = ldsfrag(Qs, wid * 16 + kl, hi * 16);
    aq[1] = ldsfrag(Qs, wid * 16 + kl, 64 + hi * 16);

    float lsum[4] = {0.f, 0.f, 0.f, 0.f};
    f32x4 o[4];
#pragma unroll
    for (int nt = 0; nt < 4; ++nt) o[nt] = f32x4{0.f, 0.f, 0.f, 0.f};

    const int qrow = wid * 16 + hi * 4;       // + r
    char* pw = (char*)Qs + wid * 2048;        // per-wave P region (own Q rows)

    for (int j = j0; j <= i; ++j) {
        const int buf = (j - j0) & 1;
        if (j < i) {                           // deferred prefetch of j+1
            const int nb = buf ^ 1;
            gload_lds16(kg0 + (j + 1) * 8192, (char*)Ks[nb] + c0 * 16);
            gload_lds16(kg1 + (j + 1) * 8192, (char*)Ks[nb] + c1 * 16);
            gload_lds16(vg0 + (j + 1) * 128,  (char*)Vs[nb] + c0 * 16);
            gload_lds16(vg1 + (j + 1) * 128,  (char*)Vs[nb] + c1 * 16);
        }

        f32x4 s[4];
#pragma unroll
        for (int nt = 0; nt < 4; ++nt) {
            s[nt] = f32x4{0.f, 0.f, 0.f, 0.f};
#pragma unroll
            for (int kk = 0; kk < 2; ++kk)
                s[nt] = __builtin_amdgcn_mfma_f32_16x16x32_bf16(
                    aq[kk], ldsfrag(Ks[buf], nt * 16 + kl, kk * 64 + hi * 16),
                    s[nt], 0, 0, 0);
        }

        if (j == i) {               // diagonal: valid iff key <= q
#pragma unroll
            for (int nt = 0; nt < 4; ++nt) {
                int key = nt * 16 + kl;
#pragma unroll
                for (int r = 0; r < 4; ++r)
                    if (key > qrow + r) s[nt][r] = -1e9f;
            }
        } else if (i - j == 8) {    // far edge: valid iff key > q
#pragma unroll
            for (int nt = 0; nt < 4; ++nt) {
                int key = nt * 16 + kl;
#pragma unroll
                for (int r = 0; r < 4; ++r)
                    if (key <= qrow + r) s[nt][r] = -1e9f;
            }
        }

#pragma unroll
        for (int nt = 0; nt < 4; ++nt)
#pragma unroll
            for (int r = 0; r < 4; ++r) {
                float p = __expf(s[nt][r]);
                s[nt][r] = p;
                lsum[r] += p;
            }

#pragma unroll
        for (int nt = 0; nt < 4; ++nt)
#pragma unroll
            for (int r = 0; r < 4; ++r) {
                int q = hi * 4 + r;
                int colb = (nt * 16 + kl) * 2;
                *(unsigned short*)(pw + q * 128 + (colb ^ ((q & 7) << 4))) =
                    f2bf(s[nt][r]);
            }

        short8 pa0 = ldsfrag(pw, kl, hi * 16);
        short8 pa1 = ldsfrag(pw, kl, 64 + hi * 16);
#pragma unroll
        for (int nt = 0; nt < 4; ++nt) {
            o[nt] = __builtin_amdgcn_mfma_f32_16x16x32_bf16(
                pa0, ldsfrag(Vs[buf], nt * 16 + kl, hi * 16), o[nt], 0, 0, 0);
            o[nt] = __builtin_amdgcn_mfma_f32_16x16x32_bf16(
                pa1, ldsfrag(Vs[buf], nt * 16 + kl, 64 + hi * 16), o[nt], 0, 0, 0);
        }

        __syncthreads();
    }

#pragma unroll
    for (int d = 1; d < 16; d <<= 1)
#pragma unroll
        for (int r = 0; r < 4; ++r) lsum[r] += __shfl_xor(lsum[r], d);

    float inv[4];
#pragma unroll
    for (int r = 0; r < 4; ++r) inv[r] = 1.0f / lsum[r];
#pragma unroll
    for (int r = 0; r < 4; ++r) {
        int tt = i * 64 + wid * 16 + hi * 4 + r;
        unsigned short* rowp = AO + ((long)(b * 4096 + tt)) * 1024 + h * 64;
#pragma unroll
        for (int nt = 0; nt < 4; ++nt)
            rowp[nt * 16 + kl] = f2bf(o[nt][r] * inv[r]);
    }
}

// ---------------------------------------------------------------------------
// Kernel 5: output projection (128x256 tiles) -> fp32 d_out. grid (64, 4).
// ---------------------------------------------------------------------------
__global__ __launch_bounds__(512, 4) void k_gemm_out(
    const unsigned short* __restrict__ AO, const unsigned short* __restrict__ wob,
    float* __restrict__ out)
{
    extern __shared__ char smem[];
    const int bx = blockIdx.x, nb = blockIdx.y;
    f32x4 acc[4][4];
    gemm_core(AO, wob, bx * 128, nb * 256, smem, acc);

    const int t = threadIdx.x, lane = t & 63, wid = t >> 6;
    const int wr = wid >> 2, wc = wid & 3, kl = lane & 15, hi = lane >> 4;
#pragma unroll
    for (int m = 0; m < 4; ++m)
#pragma unroll
        for (int r = 0; r < 4; ++r) {
            int grow = bx * 128 + wr * 64 + m * 16 + hi * 4 + r;
            float* rowp = out + (long)grow * 1024 + nb * 256 + wc * 64;
#pragma unroll
            for (int n = 0; n < 4; ++n)
                rowp[n * 16 + kl] = acc[m][n][r];
        }
}

// ---------------------------------------------------------------------------
extern "C" void kernel_launch(void* const* d_in, const int* in_sizes, int n_in,
                              void* d_out, int out_size, void* d_ws, size_t ws_size,
                              hipStream_t stream) {
    const float* x  = (const float*)d_in[0];
    const float* wq = (const float*)d_in[1];
    const float* wk = (const float*)d_in[2];
    const float* wv = (const float*)d_in[3];
    const float* wo = (const float*)d_in[4];

    char* ws = (char*)d_ws;
    const size_t MB = 1024 * 1024;
    unsigned short* xb  = (unsigned short*)(ws);            // 16 MB, reused as AO
    unsigned short* wqb = (unsigned short*)(ws + 16 * MB);  // 2 MB
    unsigned short* wkb = (unsigned short*)(ws + 18 * MB);
    unsigned short* wvb = (unsigned short*)(ws + 20 * MB);
    unsigned short* wob = (unsigned short*)(ws + 22 * MB);
    unsigned short* Qp  = (unsigned short*)(ws + 24 * MB);  // 16 MB each
    unsigned short* Kp  = (unsigned short*)(ws + 40 * MB);
    unsigned short* Vp  = (unsigned short*)(ws + 56 * MB);
    unsigned short* VTp = (unsigned short*)(ws + 72 * MB);  // end 88 MB
    unsigned short* AOp = xb;  // x no longer needed after QKV GEMM

    hipFuncSetAttribute((const void*)k_gemm_qkv,
                        hipFuncAttributeMaxDynamicSharedMemorySize, 73728);
    hipFuncSetAttribute((const void*)k_gemm_out,
                        hipFuncAttributeMaxDynamicSharedMemorySize, 73728);

    dim3 blk(256);
    k_cvt<<<dim3(8192, 5), blk, 0, stream>>>(x, wq, wk, wv, wo,
                                             xb, wqb, wkb, wvb, wob);
    k_gemm_qkv<<<dim3(64, 12), 512, 73728, stream>>>(xb, wqb, wkb, wvb,
                                                     Qp, Kp, Vp);
    k_vtrans<<<dim3(64, 32), blk, 0, stream>>>(Vp, VTp);
    k_attn<<<2048, blk, 0, stream>>>(Qp, Kp, VTp, AOp);
    k_gemm_out<<<dim3(64, 4), 512, 73728, stream>>>(AOp, wob, (float*)d_out);
}

// Round 7
// 148.300 us; speedup vs baseline: 1.0682x; 1.0010x over previous
//
#include <hip/hip_runtime.h>

#define DI static __device__ __forceinline__

typedef __attribute__((ext_vector_type(8))) short short8;  // 8 bf16 in 4 VGPRs
typedef __attribute__((ext_vector_type(4))) float f32x4;

// fp32 -> bf16 round-to-nearest-even
DI unsigned short f2bf(float f) {
    union { float f; unsigned int u; } v; v.f = f;
    unsigned int r = v.u + 0x7FFFu + ((v.u >> 16) & 1u);
    return (unsigned short)(r >> 16);
}

// async global->LDS, 16B per lane. LDS dest must be wave-uniform base + lane*16.
DI void gload_lds16(const void* g, void* l) {
    __builtin_amdgcn_global_load_lds(
        (const __attribute__((address_space(1))) void*)g,
        (__attribute__((address_space(3))) void*)l, 16, 0, 0);
}

// swizzled LDS fragment read for 128B-row tiles (attention)
DI short8 ldsfrag(const void* base, int row, int bytecol) {
    return *(const short8*)((const char*)base + row * 128 + (bytecol ^ ((row & 7) << 4)));
}

// ---------------------------------------------------------------------------
// Kernel 1: fp32 -> bf16 conversion for x and the 4 weight matrices
// ---------------------------------------------------------------------------
__global__ __launch_bounds__(256) void k_cvt(
    const float* __restrict__ x, const float* __restrict__ wq,
    const float* __restrict__ wk, const float* __restrict__ wv,
    const float* __restrict__ wo,
    unsigned short* __restrict__ xb, unsigned short* __restrict__ wqb,
    unsigned short* __restrict__ wkb, unsigned short* __restrict__ wvb,
    unsigned short* __restrict__ wob)
{
    const float* src; unsigned short* dst; int n;
    switch (blockIdx.y) {
        case 0:  src = x;  dst = xb;  n = 8388608; break;
        case 1:  src = wq; dst = wqb; n = 1048576; break;
        case 2:  src = wk; dst = wkb; n = 1048576; break;
        case 3:  src = wv; dst = wvb; n = 1048576; break;
        default: src = wo; dst = wob; n = 1048576; break;
    }
    int idx = (blockIdx.x * 256 + threadIdx.x) * 4;
    if (idx >= n) return;
    float4 v = *(const float4*)(src + idx);
    unsigned long long o = (unsigned long long)f2bf(v.x)
        | ((unsigned long long)f2bf(v.y) << 16)
        | ((unsigned long long)f2bf(v.z) << 32)
        | ((unsigned long long)f2bf(v.w) << 48);
    *(unsigned long long*)(dst + idx) = o;
}

// ---------------------------------------------------------------------------
// 128x256 GEMM core, BK=32, K=1024. C[i][j] = sum_k A[i][k]*B[j][k] (NT).
// 4 waves (1M x 4N), per-wave C = 128x64 = 8x4 16x16x32 frags -> LDS traffic
// 384 B/MFMA (vs 512 at 64x64 waves): MFMA pipe becomes dominant.
// 3 LDS buffers x (A 8KB + B 16KB) = 72KB -> 2 blocks/CU co-resident.
// Counted-vmcnt pipeline (R5/R6-proven schedule, 6 loads/stage):
//   body ks: vmcnt(6) [tile ks landed; ks+1 in flight] -> s_barrier ->
//            issue tile ks+2 into buf[(ks+2)%3] (its reads finished at step
//            ks-1, fenced by this barrier) -> 12 ds_read_b128 -> 32 MFMA.
// LDS rows are 64B (32 bf16); slot swizzle slot^=(row>>1)&3 on pre-swizzled
// global source AND fragment read (R3/R5/R6: conflicts == 0).
// ---------------------------------------------------------------------------
DI void gemm_core(const unsigned short* __restrict__ Ag,
                  const unsigned short* __restrict__ Bg,
                  int m0, int n0, char* smem, f32x4 acc[8][4])
{
    const int t = threadIdx.x, lane = t & 63;
    const int wc = t >> 6;                 // wave = N-quadrant (all waves share M)
    const int kl = lane & 15, hi = lane >> 4;

#pragma unroll
    for (int m = 0; m < 8; ++m)
#pragma unroll
        for (int n = 0; n < 4; ++n)
            acc[m][n] = f32x4{0.f, 0.f, 0.f, 0.f};

    // staging: A = 512 chunks of 16B (2/thread), B = 1024 chunks (4/thread)
    // chunk c: row = c>>2 (64B rows), slot = c&3, src slot = slot ^ ((row>>1)&3)
    const int ca0 = t,       ra0 = ca0 >> 2, sa0 = ((ca0 & 3) ^ ((ra0 >> 1) & 3)) * 8;
    const int ca1 = t + 256, ra1 = ca1 >> 2, sa1 = ((ca1 & 3) ^ ((ra1 >> 1) & 3)) * 8;
    const int cb0 = t,       rb0 = cb0 >> 2, sb0 = ((cb0 & 3) ^ ((rb0 >> 1) & 3)) * 8;
    const int cb1 = t + 256, rb1 = cb1 >> 2, sb1 = ((cb1 & 3) ^ ((rb1 >> 1) & 3)) * 8;
    const int cb2 = t + 512, rb2 = cb2 >> 2, sb2 = ((cb2 & 3) ^ ((rb2 >> 1) & 3)) * 8;
    const int cb3 = t + 768, rb3 = cb3 >> 2, sb3 = ((cb3 & 3) ^ ((rb3 >> 1) & 3)) * 8;
    const unsigned short* pa0 = Ag + (long)(m0 + ra0) * 1024 + sa0;
    const unsigned short* pa1 = Ag + (long)(m0 + ra1) * 1024 + sa1;
    const unsigned short* pb0 = Bg + (long)(n0 + rb0) * 1024 + sb0;
    const unsigned short* pb1 = Bg + (long)(n0 + rb1) * 1024 + sb1;
    const unsigned short* pb2 = Bg + (long)(n0 + rb2) * 1024 + sb2;
    const unsigned short* pb3 = Bg + (long)(n0 + rb3) * 1024 + sb3;

#define STAGE(TILE, BUF) do {                                          \
        char* _sb = smem + (BUF) * 24576;                              \
        gload_lds16(pa0 + (TILE) * 32, _sb + ca0 * 16);                \
        gload_lds16(pa1 + (TILE) * 32, _sb + ca1 * 16);                \
        gload_lds16(pb0 + (TILE) * 32, _sb + 8192 + cb0 * 16);         \
        gload_lds16(pb1 + (TILE) * 32, _sb + 8192 + cb1 * 16);        \
        gload_lds16(pb2 + (TILE) * 32, _sb + 8192 + cb2 * 16);        \
        gload_lds16(pb3 + (TILE) * 32, _sb + 8192 + cb3 * 16);        \
    } while (0)

    // prologue: tiles 0 and 1 in flight
    STAGE(0, 0);
    STAGE(1, 1);

    // fragment read offsets (swizzle key (kl>>1)&3 is m/n-independent:
    // row = base16*16 + kl, (row>>1)&3 = ((base*8 + (kl>>1)) & 3) = (kl>>1)&3)
    const int swz = ((hi ^ ((kl >> 1) & 3)) << 4);
    const int aoff = kl * 64 + swz;                       // + m*1024
    const int boff = 8192 + (wc * 64 + kl) * 64 + swz;    // + n*1024

#define KSTEP(KS, CUR, PRE, ISSUE, VM) do {                                   \
        asm volatile("s_waitcnt vmcnt(" VM ")" ::: "memory");                 \
        __builtin_amdgcn_s_barrier();                                         \
        __builtin_amdgcn_sched_barrier(0);                                    \
        if (ISSUE) STAGE((KS) + 2, PRE);                                      \
        const char* _ab = smem + (CUR) * 24576 + aoff;                        \
        const char* _bb = smem + (CUR) * 24576 + boff;                        \
        short8 _fa[8], _fb[4];                                                \
        _Pragma("unroll")                                                     \
        for (int m = 0; m < 8; ++m) _fa[m] = *(const short8*)(_ab + m * 1024);\
        _Pragma("unroll")                                                     \
        for (int n = 0; n < 4; ++n) _fb[n] = *(const short8*)(_bb + n * 1024);\
        __builtin_amdgcn_s_setprio(1);                                        \
        _Pragma("unroll")                                                     \
        for (int m = 0; m < 8; ++m)                                           \
        _Pragma("unroll")                                                     \
            for (int n = 0; n < 4; ++n)                                       \
                acc[m][n] = __builtin_amdgcn_mfma_f32_16x16x32_bf16(          \
                    _fa[m], _fb[n], acc[m][n], 0, 0, 0);                      \
        __builtin_amdgcn_s_setprio(0);                                        \
    } while (0)

    for (int u = 0; u < 10; ++u) {
        const int ks = u * 3;
        KSTEP(ks + 0, 0, 2, 1, "6");
        KSTEP(ks + 1, 1, 0, 1, "6");
        KSTEP(ks + 2, 2, 1, 1, "6");
    }
    KSTEP(30, 0, 2, 0, "6");
    KSTEP(31, 1, 0, 0, "0");
#undef KSTEP
#undef STAGE
}

// ---------------------------------------------------------------------------
// Kernel 2: fused QKV projection, 128x256 tiles. grid (64, 12): y = w*4 + nb.
// Output layout (B,H,T,hd) bf16. Q gets the 1/sqrt(hd)=0.125 scale folded in.
// ---------------------------------------------------------------------------
__global__ __launch_bounds__(256, 2) void k_gemm_qkv(
    const unsigned short* __restrict__ xb,
    const unsigned short* __restrict__ wqb, const unsigned short* __restrict__ wkb,
    const unsigned short* __restrict__ wvb,
    unsigned short* __restrict__ Qo, unsigned short* __restrict__ Ko,
    unsigned short* __restrict__ Vo)
{
    extern __shared__ char smem[];
    const int bx = blockIdx.x, by = blockIdx.y;
    const int w = by >> 2, nb = by & 3;
    const unsigned short* Bw = (w == 0) ? wqb : ((w == 1) ? wkb : wvb);
    unsigned short* Ow = (w == 0) ? Qo : ((w == 1) ? Ko : Vo);
    const float sc = (w == 0) ? 0.125f : 1.0f;

    f32x4 acc[8][4];
    gemm_core(xb, Bw, bx * 128, nb * 256, smem, acc);

    const int t = threadIdx.x, lane = t & 63;
    const int wc = t >> 6, kl = lane & 15, hi = lane >> 4;
    const int h = nb * 4 + wc;       // head (wave-uniform)
#pragma unroll
    for (int m = 0; m < 8; ++m)
#pragma unroll
        for (int r = 0; r < 4; ++r) {
            int grow = bx * 128 + m * 16 + hi * 4 + r;
            int bi = grow >> 12, tt = grow & 4095;
            unsigned short* rowp = Ow + ((long)(bi * 16 + h) * 4096 + tt) * 64;
#pragma unroll
            for (int n = 0; n < 4; ++n)
                rowp[n * 16 + kl] = f2bf(acc[m][n][r] * sc);
        }
}

// ---------------------------------------------------------------------------
// Kernel 3: V (B,H,T,hd) -> VT (B,H,hd,T), LDS-tiled 64x64 transpose.
// ---------------------------------------------------------------------------
__global__ __launch_bounds__(256) void k_vtrans(const unsigned short* __restrict__ V,
                                                unsigned short* __restrict__ VT)
{
    __shared__ unsigned short S[64 * 64];
    const int t = threadIdx.x;
    const int bh = blockIdx.y, tb = blockIdx.x;
    const unsigned short* src = V + ((long)bh * 4096 + tb * 64) * 64;
    unsigned short* dst = VT + (long)bh * 4096 * 64 + tb * 64;
    char* sb = (char*)S;
#pragma unroll
    for (int c = t; c < 512; c += 256) {
        int r = c >> 3, o8 = (c & 7) * 8;
        *(uint4*)(sb + r * 128 + ((o8 * 2) ^ (((r >> 3) & 7) << 4))) =
            *(const uint4*)(src + r * 64 + o8);
    }
    __syncthreads();
#pragma unroll
    for (int c = t; c < 512; c += 256) {
        int d = c >> 3, t0 = (c & 7) * 8;
        uint4 val;
        unsigned short* pv = (unsigned short*)&val;
#pragma unroll
        for (int jj = 0; jj < 8; ++jj) {
            int row = t0 + jj;
            pv[jj] = *(const unsigned short*)(sb + row * 128 +
                        ((d * 2) ^ (((row >> 3) & 7) << 4)));
        }
        *(uint4*)(dst + (long)d * 4096 + t0) = val;
    }
}

// ---------------------------------------------------------------------------
// Kernel 4: banded sliding-window attention (unchanged).
// ---------------------------------------------------------------------------
__global__ __launch_bounds__(256) void k_attn(
    const unsigned short* __restrict__ Q, const unsigned short* __restrict__ K,
    const unsigned short* __restrict__ VT, unsigned short* __restrict__ AO)
{
    __shared__ unsigned short Qs[4096];            // reused as P after prologue
    __shared__ unsigned short Ks[2][4096], Vs[2][4096];
    const int t = threadIdx.x, lane = t & 63, wid = t >> 6;
    const int kl = lane & 15, hi = lane >> 4;
    const int bid = blockIdx.x;
    const int sid = (bid & 7) * 256 + (bid >> 3);  // XCD-chunked (2048%8==0)
    const int i = sid & 63, bh = sid >> 6;
    const int b = bh >> 4, h = bh & 15;
    const char* qg = (const char*)(Q + ((long)bh * 4096 + i * 64) * 64);
    const char* kg = (const char*)(K + (long)bh * 4096 * 64);
    const char* vg = (const char*)(VT + (long)bh * 64 * 4096);

    const int c0 = t, c1 = t + 256;
    const int r0 = c0 >> 3, sw0 = ((c0 & 7) * 16) ^ ((r0 & 7) << 4);
    const int r1 = c1 >> 3, sw1 = ((c1 & 7) * 16) ^ ((r1 & 7) << 4);
    const char* kg0 = kg + r0 * 128 + sw0;    // + j*8192
    const char* kg1 = kg + r1 * 128 + sw1;
    const char* vg0 = vg + r0 * 8192 + sw0;   // + j*128
    const char* vg1 = vg + r1 * 8192 + sw1;

    const int j0 = (i >= 8) ? i - 8 : 0;

    gload_lds16(qg + r0 * 128 + sw0, (char*)Qs + c0 * 16);
    gload_lds16(qg + r1 * 128 + sw1, (char*)Qs + c1 * 16);
    gload_lds16(kg0 + j0 * 8192, (char*)Ks[0] + c0 * 16);
    gload_lds16(kg1 + j0 * 8192, (char*)Ks[0] + c1 * 16);
    gload_lds16(vg0 + j0 * 128,  (char*)Vs[0] + c0 * 16);
    gload_lds16(vg1 + j0 * 128,  (char*)Vs[0] + c1 * 16);
    __syncthreads();

    short8 aq[2];
    aq[0] = ldsfrag(Qs, wid * 16 + kl, hi * 16);
    aq[1] = ldsfrag(Qs, wid * 16 + kl, 64 + hi * 16);

    float lsum[4] = {0.f, 0.f, 0.f, 0.f};
    f32x4 o[4];
#pragma unroll
    for (int nt = 0; nt < 4; ++nt) o[nt] = f32x4{0.f, 0.f, 0.f, 0.f};

    const int qrow = wid * 16 + hi * 4;       // + r
    char* pw = (char*)Qs + wid * 2048;        // per-wave P region (own Q rows)

    for (int j = j0; j <= i; ++j) {
        const int buf = (j - j0) & 1;
        if (j < i) {                           // deferred prefetch of j+1
            const int nb = buf ^ 1;
            gload_lds16(kg0 + (j + 1) * 8192, (char*)Ks[nb] + c0 * 16);
            gload_lds16(kg1 + (j + 1) * 8192, (char*)Ks[nb] + c1 * 16);
            gload_lds16(vg0 + (j + 1) * 128,  (char*)Vs[nb] + c0 * 16);
            gload_lds16(vg1 + (j + 1) * 128,  (char*)Vs[nb] + c1 * 16);
        }

        f32x4 s[4];
#pragma unroll
        for (int nt = 0; nt < 4; ++nt) {
            s[nt] = f32x4{0.f, 0.f, 0.f, 0.f};
#pragma unroll
            for (int kk = 0; kk < 2; ++kk)
                s[nt] = __builtin_amdgcn_mfma_f32_16x16x32_bf16(
                    aq[kk], ldsfrag(Ks[buf], nt * 16 + kl, kk * 64 + hi * 16),
                    s[nt], 0, 0, 0);
        }

        if (j == i) {               // diagonal: valid iff key <= q
#pragma unroll
            for (int nt = 0; nt < 4; ++nt) {
                int key = nt * 16 + kl;
#pragma unroll
                for (int r = 0; r < 4; ++r)
                    if (key > qrow + r) s[nt][r] = -1e9f;
            }
        } else if (i - j == 8) {    // far edge: valid iff key > q
#pragma unroll
            for (int nt = 0; nt < 4; ++nt) {
                int key = nt * 16 + kl;
#pragma unroll
                for (int r = 0; r < 4; ++r)
                    if (key <= qrow + r) s[nt][r] = -1e9f;
            }
        }

#pragma unroll
        for (int nt = 0; nt < 4; ++nt)
#pragma unroll
            for (int r = 0; r < 4; ++r) {
                float p = __expf(s[nt][r]);
                s[nt][r] = p;
                lsum[r] += p;
            }

#pragma unroll
        for (int nt = 0; nt < 4; ++nt)
#pragma unroll
            for (int r = 0; r < 4; ++r) {
                int q = hi * 4 + r;
                int colb = (nt * 16 + kl) * 2;
                *(unsigned short*)(pw + q * 128 + (colb ^ ((q & 7) << 4))) =
                    f2bf(s[nt][r]);
            }

        short8 pa0 = ldsfrag(pw, kl, hi * 16);
        short8 pa1 = ldsfrag(pw, kl, 64 + hi * 16);
#pragma unroll
        for (int nt = 0; nt < 4; ++nt) {
            o[nt] = __builtin_amdgcn_mfma_f32_16x16x32_bf16(
                pa0, ldsfrag(Vs[buf], nt * 16 + kl, hi * 16), o[nt], 0, 0, 0);
            o[nt] = __builtin_amdgcn_mfma_f32_16x16x32_bf16(
                pa1, ldsfrag(Vs[buf], nt * 16 + kl, 64 + hi * 16), o[nt], 0, 0, 0);
        }

        __syncthreads();
    }

#pragma unroll
    for (int d = 1; d < 16; d <<= 1)
#pragma unroll
        for (int r = 0; r < 4; ++r) lsum[r] += __shfl_xor(lsum[r], d);

    float inv[4];
#pragma unroll
    for (int r = 0; r < 4; ++r) inv[r] = 1.0f / lsum[r];
#pragma unroll
    for (int r = 0; r < 4; ++r) {
        int tt = i * 64 + wid * 16 + hi * 4 + r;
        unsigned short* rowp = AO + ((long)(b * 4096 + tt)) * 1024 + h * 64;
#pragma unroll
        for (int nt = 0; nt < 4; ++nt)
            rowp[nt * 16 + kl] = f2bf(o[nt][r] * inv[r]);
    }
}

// ---------------------------------------------------------------------------
// Kernel 5: output projection (128x256 tiles) -> fp32 d_out. grid (64, 4).
// ---------------------------------------------------------------------------
__global__ __launch_bounds__(256, 2) void k_gemm_out(
    const unsigned short* __restrict__ AO, const unsigned short* __restrict__ wob,
    float* __restrict__ out)
{
    extern __shared__ char smem[];
    const int bx = blockIdx.x, nb = blockIdx.y;
    f32x4 acc[8][4];
    gemm_core(AO, wob, bx * 128, nb * 256, smem, acc);

    const int t = threadIdx.x, lane = t & 63;
    const int wc = t >> 6, kl = lane & 15, hi = lane >> 4;
#pragma unroll
    for (int m = 0; m < 8; ++m)
#pragma unroll
        for (int r = 0; r < 4; ++r) {
            int grow = bx * 128 + m * 16 + hi * 4 + r;
            float* rowp = out + (long)grow * 1024 + nb * 256 + wc * 64;
#pragma unroll
            for (int n = 0; n < 4; ++n)
                rowp[n * 16 + kl] = acc[m][n][r];
        }
}

// ---------------------------------------------------------------------------
extern "C" void kernel_launch(void* const* d_in, const int* in_sizes, int n_in,
                              void* d_out, int out_size, void* d_ws, size_t ws_size,
                              hipStream_t stream) {
    const float* x  = (const float*)d_in[0];
    const float* wq = (const float*)d_in[1];
    const float* wk = (const float*)d_in[2];
    const float* wv = (const float*)d_in[3];
    const float* wo = (const float*)d_in[4];

    char* ws = (char*)d_ws;
    const size_t MB = 1024 * 1024;
    unsigned short* xb  = (unsigned short*)(ws);            // 16 MB, reused as AO
    unsigned short* wqb = (unsigned short*)(ws + 16 * MB);  // 2 MB
    unsigned short* wkb = (unsigned short*)(ws + 18 * MB);
    unsigned short* wvb = (unsigned short*)(ws + 20 * MB);
    unsigned short* wob = (unsigned short*)(ws + 22 * MB);
    unsigned short* Qp  = (unsigned short*)(ws + 24 * MB);  // 16 MB each
    unsigned short* Kp  = (unsigned short*)(ws + 40 * MB);
    unsigned short* Vp  = (unsigned short*)(ws + 56 * MB);
    unsigned short* VTp = (unsigned short*)(ws + 72 * MB);  // end 88 MB
    unsigned short* AOp = xb;  // x no longer needed after QKV GEMM

    hipFuncSetAttribute((const void*)k_gemm_qkv,
                        hipFuncAttributeMaxDynamicSharedMemorySize, 73728);
    hipFuncSetAttribute((const void*)k_gemm_out,
                        hipFuncAttributeMaxDynamicSharedMemorySize, 73728);

    dim3 blk(256);
    k_cvt<<<dim3(8192, 5), blk, 0, stream>>>(x, wq, wk, wv, wo,
                                             xb, wqb, wkb, wvb, wob);
    k_gemm_qkv<<<dim3(64, 12), 256, 73728, stream>>>(xb, wqb, wkb, wvb,
                                                     Qp, Kp, Vp);
    k_vtrans<<<dim3(64, 32), blk, 0, stream>>>(Vp, VTp);
    k_attn<<<2048, blk, 0, stream>>>(Qp, Kp, VTp, AOp);
    k_gemm_out<<<dim3(64, 4), 256, 73728, stream>>>(AOp, wob, (float*)d_out);
}